// Round 1
// baseline (615.057 us; speedup 1.0000x reference)
//
#include <hip/hip_runtime.h>

// Segment-mean aggregation:
//   feat_map [1, C=128, Hf=512, Wf=1024] f32, seg [Hf*Wf] i32 in [0,N=400)
//   out [N, C] f32 = per-segment mean of pixel features (0 for empty segments)
//
// Strategy: memory-bound (256 MB feat read, ~41 us floor at 6.3 TB/s).
//  Phase 1: blocks = (B pixel-chunks x C/32 channel-groups). Each block
//           accumulates a 400x32 f32 table in LDS (50 KB) via ds_add_f32,
//           streaming float4 feature loads / int4 seg loads. Partials stored
//           to ws (no global atomics; ws fully overwritten -> no init pass).
//  Phase 2: one thread per (s,c); sums B partials + counts, divides.

#define NSEG_MAX 400
#define CG 32            // channels per group (LDS table = CG*400*4 = 50 KB)
#define THREADS 1024

__global__ __launch_bounds__(THREADS)
void seg_partial_kernel(const float* __restrict__ feat,
                        const int* __restrict__ seg,
                        float* __restrict__ ws_sums,   // [C][B][N]
                        float* __restrict__ ws_cnt,    // [B][N]
                        long P, int N, int B, int kIters)
{
    __shared__ float s_sum[CG * NSEG_MAX];   // [dc][400]; stride 400 words ->
                                             // random seg ids spread banks
    __shared__ float s_cnt[NSEG_MAX];

    const int tid = threadIdx.x;
    const int b   = blockIdx.x;     // pixel-chunk index
    const int g   = blockIdx.y;     // channel-group index
    const int c0  = g * CG;

    for (int i = tid; i < CG * NSEG_MAX; i += THREADS) s_sum[i] = 0.f;
    if (tid < NSEG_MAX) s_cnt[tid] = 0.f;
    __syncthreads();

    const long pixPerBlock = (long)kIters * (THREADS * 4);
    const long pbase = (long)b * pixPerBlock;

    for (int k = 0; k < kIters; ++k) {
        const long p = pbase + (long)k * (THREADS * 4) + (long)tid * 4;
        const int4 sq = *(const int4*)(seg + p);
        if (g == 0) {   // counts are channel-independent: only group 0 does them
            atomicAdd(&s_cnt[sq.x], 1.f);
            atomicAdd(&s_cnt[sq.y], 1.f);
            atomicAdd(&s_cnt[sq.z], 1.f);
            atomicAdd(&s_cnt[sq.w], 1.f);
        }
        #pragma unroll 8
        for (int dc = 0; dc < CG; ++dc) {
            const float4 v = *(const float4*)(feat + (long)(c0 + dc) * P + p);
            atomicAdd(&s_sum[dc * NSEG_MAX + sq.x], v.x);
            atomicAdd(&s_sum[dc * NSEG_MAX + sq.y], v.y);
            atomicAdd(&s_sum[dc * NSEG_MAX + sq.z], v.z);
            atomicAdd(&s_sum[dc * NSEG_MAX + sq.w], v.w);
        }
    }
    __syncthreads();

    // Flush LDS table -> global partials (plain coalesced stores).
    for (int i = tid; i < CG * N; i += THREADS) {
        const int dc = i / N;
        const int s  = i - dc * N;
        ws_sums[((long)(c0 + dc) * B + b) * N + s] = s_sum[dc * NSEG_MAX + s];
    }
    if (g == 0) {
        for (int s = tid; s < N; s += THREADS)
            ws_cnt[(long)b * N + s] = s_cnt[s];
    }
}

__global__ __launch_bounds__(256)
void seg_finalize_kernel(const float* __restrict__ ws_sums,
                         const float* __restrict__ ws_cnt,
                         float* __restrict__ out,
                         int N, int C, int B)
{
    const int t = blockIdx.x * 256 + threadIdx.x;
    if (t >= N * C) return;
    // consecutive threads -> consecutive s (coalesced partial reads)
    const int c = t / N;
    const int s = t - c * N;

    float sum = 0.f, cnt = 0.f;
    const float* ps = ws_sums + (long)c * B * N + s;
    const float* pc = ws_cnt + s;
    #pragma unroll 4
    for (int b = 0; b < B; ++b) {
        sum += ps[(long)b * N];
        cnt += pc[(long)b * N];
    }
    out[s * C + c] = (cnt > 0.f) ? (sum / cnt) : 0.f;
}

extern "C" void kernel_launch(void* const* d_in, const int* in_sizes, int n_in,
                              void* d_out, int out_size, void* d_ws, size_t ws_size,
                              hipStream_t stream)
{
    const float* feat = (const float*)d_in[0];
    const int*   seg  = (const int*)d_in[1];
    float*       out  = (float*)d_out;

    const long P = in_sizes[1];             // 512*1024 = 524288 pixels
    const int  C = (int)(in_sizes[0] / P);  // 128
    const int  N = out_size / C;            // 400

    // Pick B (pixel-chunk count) to fit workspace; B=64 needs ~13.2 MB.
    const size_t perB = (size_t)(C + 1) * (size_t)N * sizeof(float);
    int B = 64;
    while (B > 1 && ((size_t)B * perB > ws_size ||
                     (P % ((long)B * THREADS * 4)) != 0))
        B >>= 1;
    const int kIters = (int)(P / ((long)B * THREADS * 4));

    float* ws_sums = (float*)d_ws;                       // C*B*N floats
    float* ws_cnt  = ws_sums + (size_t)C * B * N;        // B*N floats

    dim3 grid1(B, C / CG);
    seg_partial_kernel<<<grid1, dim3(THREADS), 0, stream>>>(
        feat, seg, ws_sums, ws_cnt, P, N, B, kIters);

    const int total = N * C;
    seg_finalize_kernel<<<(total + 255) / 256, 256, 0, stream>>>(
        ws_sums, ws_cnt, out, N, C, B);
}